// Round 1
// 1396.989 us; speedup vs baseline: 1.0749x; 1.0749x over previous
//
#include <hip/hip_runtime.h>
#include <stdint.h>

#define N_TOKENS 16384
#define HIDDEN   1024
#define FFN      4096
#define N_EXPERTS 8
#define NBLK     (N_TOKENS / 256)    // 64 routing blocks
#define MAX_T    136                 // worst-case 256-row tiles (sum ceil(e/256) <= 136)
#define MAX_ROWS (MAX_T * 256)       // 34816
#define NB_HALF  2048                // FFN split width (H is [rows][2048])

typedef __attribute__((ext_vector_type(8))) short short8;
typedef __attribute__((ext_vector_type(4))) float f32x4;

__device__ inline unsigned short f2bf(float f) {
  union { float f; unsigned u; } c; c.f = f;
  unsigned u = c.u;
  unsigned r = (u + 0x7fffu + ((u >> 16) & 1u)) >> 16;  // RNE
  return (unsigned short)r;
}

__device__ inline void gld_lds16(const unsigned short* g, unsigned short* l) {
  __builtin_amdgcn_global_load_lds(
      (const __attribute__((address_space(1))) void*)g,
      (__attribute__((address_space(3))) void*)l, 16, 0, 0);
}

// counted-vmcnt barrier primitives (HK/T3+T4 pattern). All control flow at
// these points is block-uniform. "memory" clobber pins LDS reads / gld_lds
// issues on the correct side of each barrier.
#define VM_BAR(N) asm volatile("s_waitcnt vmcnt(" #N ")\n\ts_barrier" ::: "memory")
#define JUST_BAR() asm volatile("s_barrier" ::: "memory")
#define LGKM0()   asm volatile("s_waitcnt lgkmcnt(0)" ::: "memory")
#define PRIO1 __builtin_amdgcn_s_setprio(1)
#define PRIO0 __builtin_amdgcn_s_setprio(0)

// ---------------- gate: scores, top-2, softmax ----------------
__global__ __launch_bounds__(256) void gate_kernel(
    const float* __restrict__ x, const float* __restrict__ Wg,
    const float* __restrict__ bg, int* __restrict__ gate_idx,
    float* __restrict__ gate_w)
{
  int lane = threadIdx.x & 63;
  int wv = threadIdx.x >> 6;
  int t = blockIdx.x * 4 + wv;
  const float* xr = x + (size_t)t * HIDDEN;
  float acc[N_EXPERTS];
#pragma unroll
  for (int e = 0; e < N_EXPERTS; e++) acc[e] = 0.f;
#pragma unroll
  for (int i = 0; i < HIDDEN / 64; i++) {
    int h = i * 64 + lane;
    float xv = xr[h];
    const float4* wv4 = (const float4*)(Wg + (size_t)h * N_EXPERTS);
    float4 w01 = wv4[0], w23 = wv4[1];
    acc[0] = fmaf(xv, w01.x, acc[0]); acc[1] = fmaf(xv, w01.y, acc[1]);
    acc[2] = fmaf(xv, w01.z, acc[2]); acc[3] = fmaf(xv, w01.w, acc[3]);
    acc[4] = fmaf(xv, w23.x, acc[4]); acc[5] = fmaf(xv, w23.y, acc[5]);
    acc[6] = fmaf(xv, w23.z, acc[6]); acc[7] = fmaf(xv, w23.w, acc[7]);
  }
#pragma unroll
  for (int off = 32; off > 0; off >>= 1)
#pragma unroll
    for (int e = 0; e < N_EXPERTS; e++)
      acc[e] += __shfl_down(acc[e], off, 64);
  if (lane == 0) {
    float s[N_EXPERTS];
#pragma unroll
    for (int e = 0; e < N_EXPERTS; e++) s[e] = acc[e] + bg[e];
    int e0 = 0;
#pragma unroll
    for (int e = 1; e < N_EXPERTS; e++) if (s[e] > s[e0]) e0 = e;
    int e1 = (e0 == 0) ? 1 : 0;
#pragma unroll
    for (int e = 0; e < N_EXPERTS; e++) if (e != e0 && s[e] > s[e1]) e1 = e;
    float d = s[e1] - s[e0];
    float ex = __expf(d);
    float w0 = 1.f / (1.f + ex);
    float w1 = ex / (1.f + ex);
    gate_idx[2 * t] = e0; gate_idx[2 * t + 1] = e1;
    gate_w[2 * t] = w0;  gate_w[2 * t + 1] = w1;
  }
}

// ---------------- per-block expert histogram ----------------
__global__ __launch_bounds__(256) void count_kernel(
    const int* __restrict__ gate_idx, int* __restrict__ blockCounts)
{
  __shared__ int h[N_EXPERTS];
  if (threadIdx.x < N_EXPERTS) h[threadIdx.x] = 0;
  __syncthreads();
  int t = blockIdx.x * 256 + threadIdx.x;
  atomicAdd(&h[gate_idx[2 * t]], 1);
  atomicAdd(&h[gate_idx[2 * t + 1]], 1);
  __syncthreads();
  if (threadIdx.x < N_EXPERTS)
    blockCounts[blockIdx.x * N_EXPERTS + threadIdx.x] = h[threadIdx.x];
}

// ---------------- scan: 256-aligned expert offsets, tile->expert ----------------
__global__ void scan_kernel(const int* __restrict__ blockCounts,
                            int* __restrict__ blockBase, int* __restrict__ meta)
{
  __shared__ int totals[N_EXPERTS];
  __shared__ int offs[N_EXPERTS + 1];
  int e = threadIdx.x;
  if (e < N_EXPERTS) {
    int run = 0;
    for (int b = 0; b < NBLK; b++) {
      blockBase[b * N_EXPERTS + e] = run;
      run += blockCounts[b * N_EXPERTS + e];
    }
    totals[e] = run;
  }
  __syncthreads();
  if (threadIdx.x == 0) {
    int off = 0;
    for (int ee = 0; ee < N_EXPERTS; ee++) {
      offs[ee] = off;
      meta[16 + ee] = off;
      off += ((totals[ee] + 255) >> 8) << 8;   // 256-aligned (BM=256)
    }
    offs[N_EXPERTS] = off;
    meta[16 + N_EXPERTS] = off;
    int ntiles = off >> 8;
    meta[25] = ntiles;
    int ee = 0;
    for (int t = 0; t < ntiles; t++) {
      while (offs[ee + 1] <= (t << 8)) ee++;
      meta[32 + t] = ee;
    }
  }
  __syncthreads();
  if (e < N_EXPERTS) {
    int o = offs[e];
    for (int b = 0; b < NBLK; b++)
      blockBase[b * N_EXPERTS + e] += o;
  }
}

// ---------------- place: slot assignment via LDS cursors ----------------
__global__ __launch_bounds__(256) void place_kernel(
    const int* __restrict__ gate_idx, const float* __restrict__ gate_w,
    const int* __restrict__ blockBase, int* __restrict__ pair_token,
    float* __restrict__ pair_w)
{
  __shared__ int cur[N_EXPERTS];
  if (threadIdx.x < N_EXPERTS)
    cur[threadIdx.x] = blockBase[blockIdx.x * N_EXPERTS + threadIdx.x];
  __syncthreads();
  int t = blockIdx.x * 256 + threadIdx.x;
#pragma unroll
  for (int k = 0; k < 2; k++) {
    int e = gate_idx[2 * t + k];
    int pos = atomicAdd(&cur[e], 1);
    pair_token[pos] = t;
    pair_w[pos] = gate_w[2 * t + k];
  }
}

// ---------------- gather x rows -> bf16 Xg ----------------
__global__ __launch_bounds__(256) void gather_kernel(
    const float* __restrict__ x, const int* __restrict__ pair_token,
    unsigned short* __restrict__ Xg)
{
  int r = blockIdx.x;
  int t = pair_token[r];
  if (t < 0) return;  // pad row: poison; dropped at GEMM2 epilogue
  const float4* src = (const float4*)(x + (size_t)t * HIDDEN);
  float4 v = src[threadIdx.x];
  ushort4 o;
  o.x = f2bf(v.x); o.y = f2bf(v.y); o.z = f2bf(v.z); o.w = f2bf(v.w);
  ((ushort4*)(Xg + (size_t)r * HIDDEN))[threadIdx.x] = o;
}

// ---------------- transpose + fp32->bf16: in[E][R][C] -> out[E][C][R] ----------------
__global__ __launch_bounds__(256) void transpose_bf16_kernel(
    const float* __restrict__ in, unsigned short* __restrict__ out, int R, int C)
{
  __shared__ float tile[64][65];
  int e = blockIdx.z;
  int r0 = blockIdx.y * 64, c0 = blockIdx.x * 64;
  int tr = threadIdx.x >> 4, tc = threadIdx.x & 15;
  const float* src = in + ((size_t)e * R + r0) * C + c0;
#pragma unroll
  for (int rr = 0; rr < 4; rr++) {
    int row = rr * 16 + tr;
    float4 v = *(const float4*)(src + (size_t)row * C + tc * 4);
    tile[row][tc * 4 + 0] = v.x; tile[row][tc * 4 + 1] = v.y;
    tile[row][tc * 4 + 2] = v.z; tile[row][tc * 4 + 3] = v.w;
  }
  __syncthreads();
  unsigned short* dst = out + ((size_t)e * C + c0) * R + r0;
#pragma unroll
  for (int rr = 0; rr < 4; rr++) {
    int crow = rr * 16 + tr;
    ushort4 o;
    o.x = f2bf(tile[tc * 4 + 0][crow]);
    o.y = f2bf(tile[tc * 4 + 1][crow]);
    o.z = f2bf(tile[tc * 4 + 2][crow]);
    o.w = f2bf(tile[tc * 4 + 3][crow]);
    *(ushort4*)(dst + (size_t)crow * R + tc * 4) = o;
  }
}

// ---------------- 256x256 8-phase bf16 GEMM (T1+T2+T3/T4+T5) ----------------
// BM=BN=256, BK=64, 512 threads = 8 waves (2M x 4N), per-wave 128x64 output.
// Interleaved frag map: A row = (mi*2+wm)*16, B row = (ni*4+wn)*16 so each
// lo/hi quadrant lies in one 128-row half-tile for ALL waves.
// LDS: 2 dbuf x {A0,A1,B0,B1} x (128 rows x 64 bf16) = 128 KiB.
// Swizzle: 16B-chunk col cc ^= (row&7), applied on global SOURCE addresses
// (gld_lds dest stays linear) and identically on ds_read addresses.
// Staging: per half-tile each thread issues 2x gld_lds16 (chunks tid, tid+512).
// Phase p of tile t: [ds_read subtile | stage one half of t+1 | vmcnt(4)+bar |
// lgkmcnt(0) | setprio(1) 16xMFMA setprio(0) | bar].  FIFO vmcnt(4) after the
// stage guarantees exactly the halves the next phase reads (see derivation).
// EPI=0: H[row][hcol] = bf16(relu(acc+b1))   (A=Xg, N-window of FFN)
// EPI=1: atomicAdd(out[token][col], w*(acc+b2?))  (A=H, K-partial; bias once)
template<int EPI>
__global__ __launch_bounds__(512, 2) void moe_gemm_kernel(
    const unsigned short* __restrict__ A,    // [rows][lda] bf16
    const unsigned short* __restrict__ Bt,   // [E][nbfull][ldb] bf16
    const float* __restrict__ bias,          // [E][nbfull] or null
    unsigned short* __restrict__ Hout,       // [rows][NB_HALF]
    float* __restrict__ out,                 // [N_TOKENS][HIDDEN]
    const int* __restrict__ meta,
    const int* __restrict__ pair_token,
    const float* __restrict__ pair_w,
    int lda, int ldb, int bkoff, int klen, int nbase, int nbfull)
{
  int ntiles = meta[25];

  // T1: bijective XCD-chunked swizzle, rt-major assignment (A/H L2 locality)
  int gx = gridDim.x;
  int nwg = gx * gridDim.y;
  int lid = blockIdx.y * gx + blockIdx.x;
  int q = nwg >> 3, r8 = nwg & 7;
  int xcd = lid & 7, pos = lid >> 3;
  int aid = (xcd < r8 ? xcd * (q + 1) : r8 * (q + 1) + (xcd - r8) * q) + pos;
  int rt = aid / gx;
  int ct = aid % gx;
  if (rt >= ntiles) return;
  int row0 = rt << 8;
  int e = meta[32 + rt];

  __shared__ __align__(16) unsigned short lds[2][4][8192]; // [buf][A0,A1,B0,B1][128*64]

  int tid = threadIdx.x;
  int lane = tid & 63, wv = tid >> 6;
  int wm = wv >> 2, wn = wv & 3;
  int quad = lane >> 4, l16 = lane & 15;

  // staging precompute: chunk tid -> (row, swizzled source col)
  int r0c = tid >> 3;
  int c0c = (tid & 7) ^ (r0c & 7);                 // chunk tid+512: row+64, same col (64%8==0)
  const unsigned short* Ab = A + (size_t)row0 * lda;
  const unsigned short* Bb = Bt + ((size_t)e * nbfull + nbase + (ct << 8)) * ldb + bkoff;
  const unsigned short* gA0 = Ab + (size_t)r0c * lda + c0c * 8;
  const unsigned short* gB0 = Bb + (size_t)r0c * ldb + c0c * 8;
  size_t sA = (size_t)64 * lda, sB = (size_t)64 * ldb;

  auto STAGE = [&](int bi, int slot, const unsigned short* g, size_t s64, int k0) {
    unsigned short* l = &lds[bi][slot][0] + tid * 8;
    gld_lds16(g + k0, l);
    gld_lds16(g + s64 + k0, l + 4096);
  };

  // ds_read per-lane swizzled offsets (shorts); k = quad*8 + ks*32
  int swz0 = (quad ^ (l16 & 7)) << 3;
  int swz1 = ((quad ^ 4) ^ (l16 & 7)) << 3;
  int aoff0 = wm * 1024 + l16 * 64 + swz0;
  int aoff1 = wm * 1024 + l16 * 64 + swz1;
  int boff0 = wn * 1024 + l16 * 64 + swz0;
  int boff1 = wn * 1024 + l16 * 64 + swz1;

  f32x4 acc[8][4];
  f32x4 zero = {0.f, 0.f, 0.f, 0.f};
#pragma unroll
  for (int i = 0; i < 8; i++)
#pragma unroll
    for (int j = 0; j < 4; j++) acc[i][j] = zero;

  short8 aL[4][2], aH[4][2], bL[2][2], bH[2][2];

  auto LDA = [&](int bi, int half, short8 (&d)[4][2]) {
    const unsigned short* base = &lds[bi][half][0];
#pragma unroll
    for (int mf = 0; mf < 4; mf++) {
      d[mf][0] = *(const short8*)(base + aoff0 + mf * 2048);
      d[mf][1] = *(const short8*)(base + aoff1 + mf * 2048);
    }
  };
  auto LDB = [&](int bi, int half, short8 (&d)[2][2]) {
    const unsigned short* base = &lds[bi][2 + half][0];
#pragma unroll
    for (int nf = 0; nf < 2; nf++) {
      d[nf][0] = *(const short8*)(base + boff0 + nf * 4096);
      d[nf][1] = *(const short8*)(base + boff1 + nf * 4096);
    }
  };
  auto MM = [&](short8 (&a)[4][2], short8 (&b)[2][2], int mh, int nh) {
#pragma unroll
    for (int mf = 0; mf < 4; mf++)
#pragma unroll
      for (int nf = 0; nf < 2; nf++) {
        f32x4& c = acc[mh * 4 + mf][nh * 2 + nf];
        c = __builtin_amdgcn_mfma_f32_16x16x32_bf16(a[mf][0], b[nf][0], c, 0, 0, 0);
        c = __builtin_amdgcn_mfma_f32_16x16x32_bf16(a[mf][1], b[nf][1], c, 0, 0, 0);
      }
  };

  int NT = klen >> 6;

  // prologue: tile 0, issue order [A0,B0,A1,B1]; wait A0,B0 done
  STAGE(0, 0, gA0, sA, 0);
  STAGE(0, 2, gB0, sB, 0);
  STAGE(0, 1, gA0 + 2 * sA, sA, 0);
  STAGE(0, 3, gB0 + 2 * sB, sB, 0);
  VM_BAR(4);

  for (int t = 0; t < NT - 1; t++) {
    int bi = t & 1, nb = bi ^ 1;
    int kn = (t + 1) << 6;
    // P1: Q(lo,lo) — reads A0(t),B0(t); stage A0(t+1)
    LDA(bi, 0, aL); LDB(bi, 0, bL);
    STAGE(nb, 0, gA0, sA, kn);
    VM_BAR(4);          // => A1(t) retired (needed by P2)
    LGKM0();
    PRIO1; MM(aL, bL, 0, 0); PRIO0;
    JUST_BAR();
    // P2: Q(hi,lo) — reads A1(t); stage B0(t+1)
    LDA(bi, 1, aH);
    STAGE(nb, 2, gB0, sB, kn);
    VM_BAR(4);          // => B1(t) retired (needed by P3)
    LGKM0();
    PRIO1; MM(aH, bL, 1, 0); PRIO0;
    JUST_BAR();
    // P3: Q(lo,hi) — reads B1(t); stage A1(t+1)
    LDB(bi, 1, bH);
    STAGE(nb, 1, gA0 + 2 * sA, sA, kn);
    VM_BAR(4);
    LGKM0();
    PRIO1; MM(aL, bH, 0, 1); PRIO0;
    JUST_BAR();
    // P4: Q(hi,hi) — stage B1(t+1)
    STAGE(nb, 3, gB0 + 2 * sB, sB, kn);
    VM_BAR(4);          // => A0(t+1),B0(t+1) retired (needed by next P1)
    PRIO1; MM(aH, bH, 1, 1); PRIO0;
    JUST_BAR();
  }
  { // peeled last tile: no staging; tighter waits
    int bi = (NT - 1) & 1;
    LDA(bi, 0, aL); LDB(bi, 0, bL);
    VM_BAR(2);          // => A1(last) retired
    LGKM0();
    PRIO1; MM(aL, bL, 0, 0); PRIO0;
    JUST_BAR();
    LDA(bi, 1, aH);
    VM_BAR(0);          // => B1(last) retired
    LGKM0();
    PRIO1; MM(aH, bL, 1, 0); PRIO0;
    JUST_BAR();
    LDB(bi, 1, bH);
    LGKM0();
    PRIO1; MM(aL, bH, 0, 1); PRIO0;
    PRIO1; MM(aH, bH, 1, 1); PRIO0;
  }

  // epilogue. C/D: col=lane&15, row=quad*4+j. Global row = row0+(mi*2+wm)*16+quad*4+j,
  // global col = ct*256+(ni*4+wn)*16+l16.
  if (EPI == 0) {
#pragma unroll
    for (int mi = 0; mi < 8; mi++) {
      size_t hr = (size_t)row0 + (mi * 2 + wm) * 16 + quad * 4;
#pragma unroll
      for (int ni = 0; ni < 4; ni++) {
        int hcol = (ct << 8) + (ni * 4 + wn) * 16 + l16;
        float bb = bias[(size_t)e * nbfull + nbase + hcol];
#pragma unroll
        for (int j = 0; j < 4; j++) {
          float v = fmaxf(acc[mi][ni][j] + bb, 0.f);
          Hout[(hr + j) * (size_t)NB_HALF + hcol] = f2bf(v);
        }
      }
    }
  } else {
#pragma unroll
    for (int mi = 0; mi < 8; mi++) {
      int rbase = row0 + (mi * 2 + wm) * 16 + quad * 4;
      int tok[4]; float wgt[4];
#pragma unroll
      for (int j = 0; j < 4; j++) {
        tok[j] = pair_token[rbase + j];
        wgt[j] = pair_w[rbase + j];
      }
#pragma unroll
      for (int ni = 0; ni < 4; ni++) {
        int gcol = (ct << 8) + (ni * 4 + wn) * 16 + l16;
        float bb = bias ? bias[(size_t)e * nbfull + gcol] : 0.f;
#pragma unroll
        for (int j = 0; j < 4; j++) {
          if (tok[j] >= 0)
            atomicAdd(out + (size_t)tok[j] * HIDDEN + gcol,
                      wgt[j] * (acc[mi][ni][j] + bb));
        }
      }
    }
  }
}

extern "C" void kernel_launch(void* const* d_in, const int* in_sizes, int n_in,
                              void* d_out, int out_size, void* d_ws, size_t ws_size,
                              hipStream_t stream)
{
  const float* x  = (const float*)d_in[0];
  const float* Wg = (const float*)d_in[1];
  const float* bg = (const float*)d_in[2];
  const float* W1 = (const float*)d_in[3];
  const float* b1 = (const float*)d_in[4];
  const float* W2 = (const float*)d_in[5];
  const float* b2 = (const float*)d_in[6];
  float* out = (float*)d_out;

  // workspace carve-out (~343 MB), 256B aligned chunks
  char* ws = (char*)d_ws;
  size_t off = 0;
  auto alloc = [&](size_t bytes) {
    char* p = ws + off;
    off += (bytes + 255) & ~(size_t)255;
    return p;
  };
  int* gate_idx          = (int*)alloc((size_t)N_TOKENS * 2 * sizeof(int));
  float* gate_w          = (float*)alloc((size_t)N_TOKENS * 2 * sizeof(float));
  int* meta              = (int*)alloc(2048);
  int* blockCounts       = (int*)alloc((size_t)NBLK * N_EXPERTS * sizeof(int));
  int* blockBase         = (int*)alloc((size_t)NBLK * N_EXPERTS * sizeof(int));
  int* pair_token        = (int*)alloc((size_t)MAX_ROWS * sizeof(int));
  float* pair_w          = (float*)alloc((size_t)MAX_ROWS * sizeof(float));
  unsigned short* Xg     = (unsigned short*)alloc((size_t)MAX_ROWS * HIDDEN * 2);
  unsigned short* W1T    = (unsigned short*)alloc((size_t)N_EXPERTS * FFN * HIDDEN * 2);
  unsigned short* W2T    = (unsigned short*)alloc((size_t)N_EXPERTS * HIDDEN * FFN * 2);
  unsigned short* H      = (unsigned short*)alloc((size_t)MAX_ROWS * NB_HALF * 2);

  hipMemsetAsync(pair_token, 0xFF, (size_t)MAX_ROWS * sizeof(int), stream);  // -1
  hipMemsetAsync(out, 0, (size_t)N_TOKENS * HIDDEN * sizeof(float), stream);

  gate_kernel<<<N_TOKENS / 4, 256, 0, stream>>>(x, Wg, bg, gate_idx, gate_w);
  count_kernel<<<NBLK, 256, 0, stream>>>(gate_idx, blockCounts);
  scan_kernel<<<1, 64, 0, stream>>>(blockCounts, blockBase, meta);
  place_kernel<<<NBLK, 256, 0, stream>>>(gate_idx, gate_w, blockBase,
                                         pair_token, pair_w);
  gather_kernel<<<MAX_ROWS, 256, 0, stream>>>(x, pair_token, Xg);
  transpose_bf16_kernel<<<dim3(FFN / 64, HIDDEN / 64, N_EXPERTS), 256, 0, stream>>>(
      W1, W1T, HIDDEN, FFN);
  transpose_bf16_kernel<<<dim3(HIDDEN / 64, FFN / 64, N_EXPERTS), 256, 0, stream>>>(
      W2, W2T, FFN, HIDDEN);

  // FFN-split: for each 2048-wide half of FFN:
  //   G1: H[rows][0:2048] = relu(Xg @ W1T[:, nb:nb+2048] + b1)    (all row tiles)
  //   G2: out += pair_w * (H @ W2T[:, k=nb:nb+2048] + b2?)        (K-partial, atomic)
  for (int fh = 0; fh < 2; fh++) {
    int nb = fh * NB_HALF;
    moe_gemm_kernel<0><<<dim3(NB_HALF / 256, MAX_T), 512, 0, stream>>>(
        Xg, W1T, b1, H, nullptr, meta, nullptr, nullptr,
        HIDDEN, HIDDEN, 0, HIDDEN, nb, FFN);
    moe_gemm_kernel<1><<<dim3(HIDDEN / 256, MAX_T), 512, 0, stream>>>(
        H, W2T, fh == 0 ? b2 : nullptr, nullptr, out, meta, pair_token, pair_w,
        NB_HALF, FFN, nb, NB_HALF, 0, HIDDEN);
  }
}

// Round 2
// 1392.465 us; speedup vs baseline: 1.0784x; 1.0032x over previous
//
#include <hip/hip_runtime.h>
#include <stdint.h>

#define N_TOKENS 16384
#define HIDDEN   1024
#define FFN      4096
#define N_EXPERTS 8
#define NBLK     (N_TOKENS / 256)    // 64 routing blocks
#define MAX_T    136                 // worst-case 256-row tiles (sum ceil(e/256) <= 136)
#define MAX_ROWS (MAX_T * 256)       // 34816
#define NB_HALF  2048                // FFN split width (H is [rows][2048])

typedef __attribute__((ext_vector_type(8))) short short8;
typedef __attribute__((ext_vector_type(4))) float f32x4;

__device__ inline unsigned short f2bf(float f) {
  union { float f; unsigned u; } c; c.f = f;
  unsigned u = c.u;
  unsigned r = (u + 0x7fffu + ((u >> 16) & 1u)) >> 16;  // RNE
  return (unsigned short)r;
}

__device__ inline void gld_lds16(const unsigned short* g, unsigned short* l) {
  __builtin_amdgcn_global_load_lds(
      (const __attribute__((address_space(1))) void*)g,
      (__attribute__((address_space(3))) void*)l, 16, 0, 0);
}

// counted-vmcnt barrier primitives (m201/T3+T4 ledger). All control flow at
// these points is block-uniform.
#define VM_BAR(N) asm volatile("s_waitcnt vmcnt(" #N ")\n\ts_barrier" ::: "memory")
#define JUST_BAR() asm volatile("s_barrier" ::: "memory")
#define LGKM0()   asm volatile("s_waitcnt lgkmcnt(0)" ::: "memory")
#define PRIO1 __builtin_amdgcn_s_setprio(1)
#define PRIO0 __builtin_amdgcn_s_setprio(0)

// ---------------- gate: scores, top-2, softmax ----------------
__global__ __launch_bounds__(256) void gate_kernel(
    const float* __restrict__ x, const float* __restrict__ Wg,
    const float* __restrict__ bg, int* __restrict__ gate_idx,
    float* __restrict__ gate_w)
{
  int lane = threadIdx.x & 63;
  int wv = threadIdx.x >> 6;
  int t = blockIdx.x * 4 + wv;
  const float* xr = x + (size_t)t * HIDDEN;
  float acc[N_EXPERTS];
#pragma unroll
  for (int e = 0; e < N_EXPERTS; e++) acc[e] = 0.f;
#pragma unroll
  for (int i = 0; i < HIDDEN / 64; i++) {
    int h = i * 64 + lane;
    float xv = xr[h];
    const float4* wv4 = (const float4*)(Wg + (size_t)h * N_EXPERTS);
    float4 w01 = wv4[0], w23 = wv4[1];
    acc[0] = fmaf(xv, w01.x, acc[0]); acc[1] = fmaf(xv, w01.y, acc[1]);
    acc[2] = fmaf(xv, w01.z, acc[2]); acc[3] = fmaf(xv, w01.w, acc[3]);
    acc[4] = fmaf(xv, w23.x, acc[4]); acc[5] = fmaf(xv, w23.y, acc[5]);
    acc[6] = fmaf(xv, w23.z, acc[6]); acc[7] = fmaf(xv, w23.w, acc[7]);
  }
#pragma unroll
  for (int off = 32; off > 0; off >>= 1)
#pragma unroll
    for (int e = 0; e < N_EXPERTS; e++)
      acc[e] += __shfl_down(acc[e], off, 64);
  if (lane == 0) {
    float s[N_EXPERTS];
#pragma unroll
    for (int e = 0; e < N_EXPERTS; e++) s[e] = acc[e] + bg[e];
    int e0 = 0;
#pragma unroll
    for (int e = 1; e < N_EXPERTS; e++) if (s[e] > s[e0]) e0 = e;
    int e1 = (e0 == 0) ? 1 : 0;
#pragma unroll
    for (int e = 0; e < N_EXPERTS; e++) if (e != e0 && s[e] > s[e1]) e1 = e;
    float d = s[e1] - s[e0];
    float ex = __expf(d);
    float w0 = 1.f / (1.f + ex);
    float w1 = ex / (1.f + ex);
    gate_idx[2 * t] = e0; gate_idx[2 * t + 1] = e1;
    gate_w[2 * t] = w0;  gate_w[2 * t + 1] = w1;
  }
}

// ---------------- per-block expert histogram ----------------
__global__ __launch_bounds__(256) void count_kernel(
    const int* __restrict__ gate_idx, int* __restrict__ blockCounts)
{
  __shared__ int h[N_EXPERTS];
  if (threadIdx.x < N_EXPERTS) h[threadIdx.x] = 0;
  __syncthreads();
  int t = blockIdx.x * 256 + threadIdx.x;
  atomicAdd(&h[gate_idx[2 * t]], 1);
  atomicAdd(&h[gate_idx[2 * t + 1]], 1);
  __syncthreads();
  if (threadIdx.x < N_EXPERTS)
    blockCounts[blockIdx.x * N_EXPERTS + threadIdx.x] = h[threadIdx.x];
}

// ---------------- scan: 256-aligned expert offsets, tile->expert ----------------
__global__ void scan_kernel(const int* __restrict__ blockCounts,
                            int* __restrict__ blockBase, int* __restrict__ meta)
{
  __shared__ int totals[N_EXPERTS];
  __shared__ int offs[N_EXPERTS + 1];
  int e = threadIdx.x;
  if (e < N_EXPERTS) {
    int run = 0;
    for (int b = 0; b < NBLK; b++) {
      blockBase[b * N_EXPERTS + e] = run;
      run += blockCounts[b * N_EXPERTS + e];
    }
    totals[e] = run;
  }
  __syncthreads();
  if (threadIdx.x == 0) {
    int off = 0;
    for (int ee = 0; ee < N_EXPERTS; ee++) {
      offs[ee] = off;
      meta[16 + ee] = off;
      off += ((totals[ee] + 255) >> 8) << 8;   // 256-aligned (BM=256)
    }
    offs[N_EXPERTS] = off;
    meta[16 + N_EXPERTS] = off;
    int ntiles = off >> 8;
    meta[25] = ntiles;
    int ee = 0;
    for (int t = 0; t < ntiles; t++) {
      while (offs[ee + 1] <= (t << 8)) ee++;
      meta[32 + t] = ee;
    }
  }
  __syncthreads();
  if (e < N_EXPERTS) {
    int o = offs[e];
    for (int b = 0; b < NBLK; b++)
      blockBase[b * N_EXPERTS + e] += o;
  }
}

// ---------------- place: slot assignment via LDS cursors ----------------
__global__ __launch_bounds__(256) void place_kernel(
    const int* __restrict__ gate_idx, const float* __restrict__ gate_w,
    const int* __restrict__ blockBase, int* __restrict__ pair_token,
    float* __restrict__ pair_w)
{
  __shared__ int cur[N_EXPERTS];
  if (threadIdx.x < N_EXPERTS)
    cur[threadIdx.x] = blockBase[blockIdx.x * N_EXPERTS + threadIdx.x];
  __syncthreads();
  int t = blockIdx.x * 256 + threadIdx.x;
#pragma unroll
  for (int k = 0; k < 2; k++) {
    int e = gate_idx[2 * t + k];
    int pos = atomicAdd(&cur[e], 1);
    pair_token[pos] = t;
    pair_w[pos] = gate_w[2 * t + k];
  }
}

// ---------------- gather x rows -> bf16 Xg ----------------
__global__ __launch_bounds__(256) void gather_kernel(
    const float* __restrict__ x, const int* __restrict__ pair_token,
    unsigned short* __restrict__ Xg)
{
  int r = blockIdx.x;
  int t = pair_token[r];
  if (t < 0) return;  // pad row: poison; dropped at GEMM2 epilogue
  const float4* src = (const float4*)(x + (size_t)t * HIDDEN);
  float4 v = src[threadIdx.x];
  ushort4 o;
  o.x = f2bf(v.x); o.y = f2bf(v.y); o.z = f2bf(v.z); o.w = f2bf(v.w);
  ((ushort4*)(Xg + (size_t)r * HIDDEN))[threadIdx.x] = o;
}

// ---------------- transpose + fp32->bf16: in[E][R][C] -> out[E][C][R] ----------------
__global__ __launch_bounds__(256) void transpose_bf16_kernel(
    const float* __restrict__ in, unsigned short* __restrict__ out, int R, int C)
{
  __shared__ float tile[64][65];
  int e = blockIdx.z;
  int r0 = blockIdx.y * 64, c0 = blockIdx.x * 64;
  int tr = threadIdx.x >> 4, tc = threadIdx.x & 15;
  const float* src = in + ((size_t)e * R + r0) * C + c0;
#pragma unroll
  for (int rr = 0; rr < 4; rr++) {
    int row = rr * 16 + tr;
    float4 v = *(const float4*)(src + (size_t)row * C + tc * 4);
    tile[row][tc * 4 + 0] = v.x; tile[row][tc * 4 + 1] = v.y;
    tile[row][tc * 4 + 2] = v.z; tile[row][tc * 4 + 3] = v.w;
  }
  __syncthreads();
  unsigned short* dst = out + ((size_t)e * C + c0) * R + r0;
#pragma unroll
  for (int rr = 0; rr < 4; rr++) {
    int crow = rr * 16 + tr;
    ushort4 o;
    o.x = f2bf(tile[tc * 4 + 0][crow]);
    o.y = f2bf(tile[tc * 4 + 1][crow]);
    o.z = f2bf(tile[tc * 4 + 2][crow]);
    o.w = f2bf(tile[tc * 4 + 3][crow]);
    *(ushort4*)(dst + (size_t)crow * R + tc * 4) = o;
  }
}

// ---------------- 256x256 bf16 GEMM, m201 wait ledger ----------------
// BM=BN=256, BK=64, 512 threads = 8 waves (2M x 4N), per-wave 128x64 output.
// LDS: lds[buf][slot][128*64], slots: 0=A-lo,1=A-hi,2=B-lo,3=B-hi. 128 KiB.
// Swizzle: 16B-chunk col cc ^= (row&7) via pre-swizzled global SOURCE
// (gld_lds dest linear) + identical XOR on ds_read addresses.
// Wait ledger (per wave; 2 gld_lds per STAGE): steady-state invariant at tile
// entry = 6 outstanding = [A0,B0,A1](t+1). Phases:
//  P1: LD Alo,Blo | STAGE B1(t+1)->8  | bar | lgkm0 | 16 MFMA Q(lo,lo) | bar
//  P2: LD Bhi     | STAGE A0(t+2)->10 | bar | lgkm0 | 16 MFMA Q(lo,hi) | bar
//  P3: LD Ahi     | STAGE B0(t+2)->12 | bar | lgkm0 | 16 MFMA Q(hi,lo) | bar
//  P4:              STAGE A1(t+2)->14 | vmcnt(6)+bar | 16 MFMA Q(hi,hi) | bar
// vmcnt(6) retires all of t+1 (FIFO); lead per half-tile >= 4 phases.
// t+2 stages write the CURRENT buffer's regions whose last ds_read completed
// before the previous trailing barrier (WAR-safe). Prologue 14 loads ->
// vmcnt(6); tail drains 6->4->2->0; last tile reads only.
// EPI=0: H[row][hcol] = bf16(relu(acc+b1))   (A=Xg, N-window of FFN)
// EPI=1: atomicAdd(out[token][col], w*(acc+b2?))  (A=H, K-partial; bias once)
template<int EPI>
__global__ __launch_bounds__(512, 2) void moe_gemm_kernel(
    const unsigned short* __restrict__ A,    // [rows][lda] bf16
    const unsigned short* __restrict__ Bt,   // [E][nbfull][ldb] bf16
    const float* __restrict__ bias,          // [E][nbfull] or null
    unsigned short* __restrict__ Hout,       // [rows][NB_HALF]
    float* __restrict__ out,                 // [N_TOKENS][HIDDEN]
    const int* __restrict__ meta,
    const int* __restrict__ pair_token,
    const float* __restrict__ pair_w,
    int lda, int ldb, int bkoff, int klen, int nbase, int nbfull)
{
  int ntiles = meta[25];

  // T1: bijective XCD-chunked swizzle, rt-major assignment (A/H L2 locality)
  int gx = gridDim.x;
  int nwg = gx * gridDim.y;
  int lid = blockIdx.y * gx + blockIdx.x;
  int q = nwg >> 3, r8 = nwg & 7;
  int xcd = lid & 7, pos = lid >> 3;
  int aid = (xcd < r8 ? xcd * (q + 1) : r8 * (q + 1) + (xcd - r8) * q) + pos;
  int rt = aid / gx;
  int ct = aid % gx;
  if (rt >= ntiles) return;
  int row0 = rt << 8;
  int e = meta[32 + rt];

  __shared__ __align__(16) unsigned short lds[2][4][8192]; // [buf][Alo,Ahi,Blo,Bhi]

  int tid = threadIdx.x;
  int lane = tid & 63, wv = tid >> 6;
  int wm = wv >> 2, wn = wv & 3;
  int quad = lane >> 4, l16 = lane & 15;

  // staging precompute: chunk tid -> (row, swizzled source col)
  int r0c = tid >> 3;
  int c0c = (tid & 7) ^ (r0c & 7);   // chunk tid+512: row+64, same col (64%8==0)
  const unsigned short* Ab = A + (size_t)row0 * lda;
  const unsigned short* Bb = Bt + ((size_t)e * nbfull + nbase + (ct << 8)) * ldb + bkoff;
  const unsigned short* gA0 = Ab + (size_t)r0c * lda + c0c * 8;
  const unsigned short* gB0 = Bb + (size_t)r0c * ldb + c0c * 8;
  size_t sA = (size_t)64 * lda, sB = (size_t)64 * ldb;

  auto STAGE = [&](int bi, int slot, const unsigned short* g, size_t s64, int k0) {
    unsigned short* l = &lds[bi][slot][0] + tid * 8;
    gld_lds16(g + k0, l);
    gld_lds16(g + s64 + k0, l + 4096);
  };

  // ds_read per-lane swizzled offsets (shorts); k = quad*8 + ks*32
  int swz0 = (quad ^ (l16 & 7)) << 3;
  int swz1 = ((quad ^ 4) ^ (l16 & 7)) << 3;
  int aoff0 = wm * 1024 + l16 * 64 + swz0;
  int aoff1 = wm * 1024 + l16 * 64 + swz1;
  int boff0 = wn * 1024 + l16 * 64 + swz0;
  int boff1 = wn * 1024 + l16 * 64 + swz1;

  f32x4 acc[8][4];
  f32x4 zero = {0.f, 0.f, 0.f, 0.f};
#pragma unroll
  for (int i = 0; i < 8; i++)
#pragma unroll
    for (int j = 0; j < 4; j++) acc[i][j] = zero;

  short8 aL[4][2], aH[4][2], bL[2][2], bH[2][2];

  auto LDA = [&](int bi, int half, short8 (&d)[4][2]) {
    const unsigned short* base = &lds[bi][half][0];
#pragma unroll
    for (int mf = 0; mf < 4; mf++) {
      d[mf][0] = *(const short8*)(base + aoff0 + mf * 2048);
      d[mf][1] = *(const short8*)(base + aoff1 + mf * 2048);
    }
  };
  auto LDB = [&](int bi, int half, short8 (&d)[2][2]) {
    const unsigned short* base = &lds[bi][2 + half][0];
#pragma unroll
    for (int nf = 0; nf < 2; nf++) {
      d[nf][0] = *(const short8*)(base + boff0 + nf * 4096);
      d[nf][1] = *(const short8*)(base + boff1 + nf * 4096);
    }
  };
  auto MM = [&](short8 (&a)[4][2], short8 (&b)[2][2], int mh, int nh) {
#pragma unroll
    for (int mf = 0; mf < 4; mf++)
#pragma unroll
      for (int nf = 0; nf < 2; nf++) {
        f32x4& c = acc[mh * 4 + mf][nh * 2 + nf];
        c = __builtin_amdgcn_mfma_f32_16x16x32_bf16(a[mf][0], b[nf][0], c, 0, 0, 0);
        c = __builtin_amdgcn_mfma_f32_16x16x32_bf16(a[mf][1], b[nf][1], c, 0, 0, 0);
      }
  };

  int NT = klen >> 6;   // >= 3 always here (16 or 32)

  // prologue: tile0 fully + tile1 {A0,B0,A1} = 14 loads; retire tile0
  STAGE(0, 0, gA0, sA, 0);
  STAGE(0, 2, gB0, sB, 0);
  STAGE(0, 1, gA0 + 2 * sA, sA, 0);
  STAGE(0, 3, gB0 + 2 * sB, sB, 0);
  STAGE(1, 0, gA0, sA, 64);
  STAGE(1, 2, gB0, sB, 64);
  STAGE(1, 1, gA0 + 2 * sA, sA, 64);
  VM_BAR(6);

  for (int t = 0; t <= NT - 3; t++) {
    int bi = t & 1, nb = bi ^ 1;
    int kc = (t + 1) << 6, kn = (t + 2) << 6;
    // P1
    LDA(bi, 0, aL); LDB(bi, 0, bL);
    STAGE(nb, 3, gB0 + 2 * sB, sB, kc);
    JUST_BAR();
    LGKM0();
    PRIO1; MM(aL, bL, 0, 0); PRIO0;
    JUST_BAR();
    // P2
    LDB(bi, 1, bH);
    STAGE(bi, 0, gA0, sA, kn);
    JUST_BAR();
    LGKM0();
    PRIO1; MM(aL, bH, 0, 1); PRIO0;
    JUST_BAR();
    // P3
    LDA(bi, 1, aH);
    STAGE(bi, 2, gB0, sB, kn);
    JUST_BAR();
    LGKM0();
    PRIO1; MM(aH, bL, 1, 0); PRIO0;
    JUST_BAR();
    // P4
    STAGE(bi, 1, gA0 + 2 * sA, sA, kn);
    VM_BAR(6);           // retire all of t+1 (FIFO); leave [A0,B0,A1](t+2)
    PRIO1; MM(aH, bH, 1, 1); PRIO0;
    JUST_BAR();
  }
  { // tile NT-2: stage only B1(NT-1); graded drain 6->4->2->0
    int bi = (NT - 2) & 1, nb = bi ^ 1;
    int kc = (NT - 1) << 6;
    LDA(bi, 0, aL); LDB(bi, 0, bL);
    STAGE(nb, 3, gB0 + 2 * sB, sB, kc);
    VM_BAR(6);
    LGKM0();
    PRIO1; MM(aL, bL, 0, 0); PRIO0;
    JUST_BAR();
    LDB(bi, 1, bH);
    VM_BAR(4);
    LGKM0();
    PRIO1; MM(aL, bH, 0, 1); PRIO0;
    JUST_BAR();
    LDA(bi, 1, aH);
    VM_BAR(2);
    LGKM0();
    PRIO1; MM(aH, bL, 1, 0); PRIO0;
    JUST_BAR();
    VM_BAR(0);           // tile NT-1 fully resident
    PRIO1; MM(aH, bH, 1, 1); PRIO0;
    JUST_BAR();
  }
  { // last tile: reads only, no barriers needed between quadrants
    int bi = (NT - 1) & 1;
    LDA(bi, 0, aL); LDB(bi, 0, bL);
    LDB(bi, 1, bH); LDA(bi, 1, aH);
    LGKM0();
    PRIO1;
    MM(aL, bL, 0, 0); MM(aL, bH, 0, 1);
    MM(aH, bL, 1, 0); MM(aH, bH, 1, 1);
    PRIO0;
  }

  // epilogue. C/D: col=lane&15, row=quad*4+j. Global row = row0+(mi*2+wm)*16+quad*4+j,
  // global col = ct*256+(ni*4+wn)*16+l16.
  if (EPI == 0) {
#pragma unroll
    for (int mi = 0; mi < 8; mi++) {
      size_t hr = (size_t)row0 + (mi * 2 + wm) * 16 + quad * 4;
#pragma unroll
      for (int ni = 0; ni < 4; ni++) {
        int hcol = (ct << 8) + (ni * 4 + wn) * 16 + l16;
        float bb = bias[(size_t)e * nbfull + nbase + hcol];
#pragma unroll
        for (int j = 0; j < 4; j++) {
          float v = fmaxf(acc[mi][ni][j] + bb, 0.f);
          Hout[(hr + j) * (size_t)NB_HALF + hcol] = f2bf(v);
        }
      }
    }
  } else {
#pragma unroll
    for (int mi = 0; mi < 8; mi++) {
      int rbase = row0 + (mi * 2 + wm) * 16 + quad * 4;
      int tok[4]; float wgt[4];
#pragma unroll
      for (int j = 0; j < 4; j++) {
        tok[j] = pair_token[rbase + j];
        wgt[j] = pair_w[rbase + j];
      }
#pragma unroll
      for (int ni = 0; ni < 4; ni++) {
        int gcol = (ct << 8) + (ni * 4 + wn) * 16 + l16;
        float bb = bias ? bias[(size_t)e * nbfull + gcol] : 0.f;
#pragma unroll
        for (int j = 0; j < 4; j++) {
          if (tok[j] >= 0)
            atomicAdd(out + (size_t)tok[j] * HIDDEN + gcol,
                      wgt[j] * (acc[mi][ni][j] + bb));
        }
      }
    }
  }
}

extern "C" void kernel_launch(void* const* d_in, const int* in_sizes, int n_in,
                              void* d_out, int out_size, void* d_ws, size_t ws_size,
                              hipStream_t stream)
{
  const float* x  = (const float*)d_in[0];
  const float* Wg = (const float*)d_in[1];
  const float* bg = (const float*)d_in[2];
  const float* W1 = (const float*)d_in[3];
  const float* b1 = (const float*)d_in[4];
  const float* W2 = (const float*)d_in[5];
  const float* b2 = (const float*)d_in[6];
  float* out = (float*)d_out;

  // workspace carve-out (~343 MB), 256B aligned chunks
  char* ws = (char*)d_ws;
  size_t off = 0;
  auto alloc = [&](size_t bytes) {
    char* p = ws + off;
    off += (bytes + 255) & ~(size_t)255;
    return p;
  };
  int* gate_idx          = (int*)alloc((size_t)N_TOKENS * 2 * sizeof(int));
  float* gate_w          = (float*)alloc((size_t)N_TOKENS * 2 * sizeof(float));
  int* meta              = (int*)alloc(2048);
  int* blockCounts       = (int*)alloc((size_t)NBLK * N_EXPERTS * sizeof(int));
  int* blockBase         = (int*)alloc((size_t)NBLK * N_EXPERTS * sizeof(int));
  int* pair_token        = (int*)alloc((size_t)MAX_ROWS * sizeof(int));
  float* pair_w          = (float*)alloc((size_t)MAX_ROWS * sizeof(float));
  unsigned short* Xg     = (unsigned short*)alloc((size_t)MAX_ROWS * HIDDEN * 2);
  unsigned short* W1T    = (unsigned short*)alloc((size_t)N_EXPERTS * FFN * HIDDEN * 2);
  unsigned short* W2T    = (unsigned short*)alloc((size_t)N_EXPERTS * HIDDEN * FFN * 2);
  unsigned short* H      = (unsigned short*)alloc((size_t)MAX_ROWS * NB_HALF * 2);

  hipMemsetAsync(pair_token, 0xFF, (size_t)MAX_ROWS * sizeof(int), stream);  // -1
  hipMemsetAsync(out, 0, (size_t)N_TOKENS * HIDDEN * sizeof(float), stream);

  gate_kernel<<<N_TOKENS / 4, 256, 0, stream>>>(x, Wg, bg, gate_idx, gate_w);
  count_kernel<<<NBLK, 256, 0, stream>>>(gate_idx, blockCounts);
  scan_kernel<<<1, 64, 0, stream>>>(blockCounts, blockBase, meta);
  place_kernel<<<NBLK, 256, 0, stream>>>(gate_idx, gate_w, blockBase,
                                         pair_token, pair_w);
  gather_kernel<<<MAX_ROWS, 256, 0, stream>>>(x, pair_token, Xg);
  transpose_bf16_kernel<<<dim3(FFN / 64, HIDDEN / 64, N_EXPERTS), 256, 0, stream>>>(
      W1, W1T, HIDDEN, FFN);
  transpose_bf16_kernel<<<dim3(HIDDEN / 64, FFN / 64, N_EXPERTS), 256, 0, stream>>>(
      W2, W2T, FFN, HIDDEN);

  // FFN-split: for each 2048-wide half of FFN:
  //   G1: H[rows][0:2048] = relu(Xg @ W1T[:, nb:nb+2048] + b1)    (all row tiles)
  //   G2: out += pair_w * (H @ W2T[:, k=nb:nb+2048] + b2?)        (K-partial, atomic)
  for (int fh = 0; fh < 2; fh++) {
    int nb = fh * NB_HALF;
    moe_gemm_kernel<0><<<dim3(NB_HALF / 256, MAX_T), 512, 0, stream>>>(
        Xg, W1T, b1, H, nullptr, meta, nullptr, nullptr,
        HIDDEN, HIDDEN, 0, HIDDEN, nb, FFN);
    moe_gemm_kernel<1><<<dim3(HIDDEN / 256, MAX_T), 512, 0, stream>>>(
        H, W2T, fh == 0 ? b2 : nullptr, nullptr, out, meta, pair_token, pair_w,
        NB_HALF, FFN, nb, NB_HALF, 0, HIDDEN);
  }
}